// Round 13
// baseline (12194.164 us; speedup 1.0000x reference)
//
#include <hip/hip_runtime.h>
#include <stdint.h>
#include <math.h>

typedef _Float16 f16;
typedef _Float16 f16x4 __attribute__((ext_vector_type(4)));
typedef _Float16 f16x8 __attribute__((ext_vector_type(8)));
typedef float f32x4 __attribute__((ext_vector_type(4)));

#define LO_SCALE 2048.0f
#define INV_LO_SCALE (1.0f/2048.0f)
#define LOG2E 1.4426950408889634f
#define MFMA16(a, b, c) __builtin_amdgcn_mfma_f32_16x16x32_f16(a, b, c, 0, 0, 0)

__device__ __forceinline__ void split1(float x, f16 &hi, f16 &lo) {
    f16 h = (f16)x;
    hi = h;
    lo = (f16)((x - (float)h) * LO_SCALE);
}

__device__ __forceinline__ float fexp2(float x) {
#if __has_builtin(__builtin_amdgcn_exp2f)
    return __builtin_amdgcn_exp2f(x);
#else
    return exp2f(x);
#endif
}
__device__ __forceinline__ float flog2(float x) {
#if __has_builtin(__builtin_amdgcn_logf)
    return __builtin_amdgcn_logf(x);
#else
    return log2f(x);
#endif
}

#define GLOAD16(g, l) __builtin_amdgcn_global_load_lds( \
    (const __attribute__((address_space(1))) void*)(g), \
    (__attribute__((address_space(3))) void*)(l), 16, 0, 0)

// ---------------------------------------------------------------------------
// m-stripe XCD swizzle: chunk c = s&7 owns m-tiles [c*MT/8,(c+1)*MT/8),
// n iterates FASTEST within a chunk. Requires gridDim.x % 8 == 0.
// ---------------------------------------------------------------------------
__device__ __forceinline__ void swz_decode(int &mi, int &ni)
{
    const int NN = gridDim.y;
    int s = blockIdx.x + blockIdx.y * gridDim.x;
    const int c = s & 7;
    const int idx = s >> 3;
    const int mchunk = gridDim.x >> 3;
    const int md = idx / NN;
    mi = c * mchunk + md;
    ni = idx - md * NN;
}

// ---------------------------------------------------------------------------
// Epilogue writers. EPI2: Q,K,V all head-major [bh][lt][d].
// ---------------------------------------------------------------------------
template<int EPI>
__device__ __forceinline__ void epi_write(float val, int row, int col, int N,
                                          float* __restrict__ C,
                                          f16* __restrict__ Oh, f16* __restrict__ Ol,
                                          f16* __restrict__ X2h, f16* __restrict__ X2l,
                                          f16* __restrict__ X3h, f16* __restrict__ X3l)
{
    if constexpr (EPI == 0) {
        C[(size_t)row * N + col] = val;
    } else if constexpr (EPI == 1) {
        float ge = 0.5f * val * (1.0f + erff(val * 0.70710678118654752440f));
        f16 hi, lo;
        split1(ge, hi, lo);
        size_t o = (size_t)row * N + col;
        Oh[o] = hi;
        Ol[o] = lo;
    } else {
        int sect = col >= 1536 ? 2 : (col >= 768 ? 1 : 0);
        int cc = col - sect * 768;
        int hd = cc >> 6;
        int d = cc & 63;
        int bh = (row >> 8) * 12 + hd;
        int lt = row & 255;
        f16 hi, lo;
        split1(val, hi, lo);
        size_t o = ((size_t)bh * 256 + lt) * 64 + d;
        if (sect == 0)      { Oh[o] = hi;  Ol[o] = lo; }
        else if (sect == 1) { X2h[o] = hi; X2l[o] = lo; }
        else                { X3h[o] = hi; X3l[o] = lo; }
    }
}

// ---------------------------------------------------------------------------
// Shared GEMM body pieces (128x128 tile, 4 waves 2x2, per-wave 64x64, BK=32,
// K-block-major LDS layout, m-stripe XCD swizzle, setprio around MFMA).
// gemm128s: SINGLE-buffered 32KB LDS -> 4 blocks/CU capacity (m97 replica;
//           co-resident blocks hide the stage latency). For QKV + FF1.
// gemm128 : double-buffered 64KB (2 blocks/CU). For WO + FF2 (grid 192 --
//           co-residency grid-limited anyway).
// ---------------------------------------------------------------------------
template<int EPI>
__global__ __launch_bounds__(256, 4)
void gemm128s(const f16* __restrict__ Ah, const f16* __restrict__ Al,
              const f16* __restrict__ Bh, const f16* __restrict__ Bl,
              const float* __restrict__ bias, float* __restrict__ C,
              f16* __restrict__ Oh, f16* __restrict__ Ol,
              f16* __restrict__ X2h, f16* __restrict__ X2l,
              f16* __restrict__ X3h, f16* __restrict__ X3l, int K, int N)
{
    __shared__ f16 smem[16384];   // [arr(Ah,Al,Bh,Bl)][4096] single buffer

    int mi, ni;
    swz_decode(mi, ni);
    const int m0 = mi * 128;
    const int n0 = ni * 128;

    const int tid = threadIdx.x;
    const int lane = tid & 63;
    const int w = tid >> 6;
    const int l15 = lane & 15;
    const int lg = lane >> 4;

    f32x4 accm[4][4];
    f32x4 accc[4][4];
#pragma unroll
    for (int i = 0; i < 4; ++i)
#pragma unroll
        for (int j = 0; j < 4; ++j) {
            accm[i][j] = (f32x4){0.f, 0.f, 0.f, 0.f};
            accc[i][j] = (f32x4){0.f, 0.f, 0.f, 0.f};
        }

    const f16* gA0 = Ah + (size_t)(m0 + w * 32 + l15) * K + lg * 8;
    const f16* gA1 = gA0 + 16 * (size_t)K;
    const f16* gAl0 = Al + (size_t)(m0 + w * 32 + l15) * K + lg * 8;
    const f16* gAl1 = gAl0 + 16 * (size_t)K;
    const f16* gB0 = Bh + (size_t)(n0 + w * 32 + l15) * K + lg * 8;
    const f16* gB1 = gB0 + 16 * (size_t)K;
    const f16* gBl0 = Bl + (size_t)(n0 + w * 32 + l15) * K + lg * 8;
    const f16* gBl1 = gBl0 + 16 * (size_t)K;
    const int ldsb0 = w * 1024;
    const int ldsb1 = w * 1024 + 512;

    const int nt = K >> 5;
    const int fro = lg * 128 + l15 * 8;
    const int wrg = (w >> 1) * 4;
    const int wcg = (w & 1) * 4;

    for (int t = 0; t < nt; ++t) {
        const int k0 = t * 32;
        if (t) __syncthreads();   // all waves done reading the buffer
        GLOAD16(gA0 + k0, smem + ldsb0);
        GLOAD16(gA1 + k0, smem + ldsb1);
        GLOAD16(gAl0 + k0, smem + 4096 + ldsb0);
        GLOAD16(gAl1 + k0, smem + 4096 + ldsb1);
        GLOAD16(gB0 + k0, smem + 8192 + ldsb0);
        GLOAD16(gB1 + k0, smem + 8192 + ldsb1);
        GLOAD16(gBl0 + k0, smem + 12288 + ldsb0);
        GLOAD16(gBl1 + k0, smem + 12288 + ldsb1);
        __syncthreads();          // vmcnt(0) drain: staged data visible

        f16x8 fbh[4], fbl[4];
#pragma unroll
        for (int ni2 = 0; ni2 < 4; ++ni2) {
            int offb = 8192 + (wcg + ni2) * 512 + fro;
            fbh[ni2] = *(const f16x8*)(smem + offb);
            fbl[ni2] = *(const f16x8*)(smem + offb + 4096);
        }
#pragma unroll
        for (int mi2 = 0; mi2 < 4; ++mi2) {
            int offa = (wrg + mi2) * 512 + fro;
            f16x8 fah = *(const f16x8*)(smem + offa);
            f16x8 fal = *(const f16x8*)(smem + offa + 4096);
            __builtin_amdgcn_s_setprio(1);
#pragma unroll
            for (int ni2 = 0; ni2 < 4; ++ni2) {
                accm[mi2][ni2] = MFMA16(fah, fbh[ni2], accm[mi2][ni2]);
                accc[mi2][ni2] = MFMA16(fah, fbl[ni2], accc[mi2][ni2]);
                accc[mi2][ni2] = MFMA16(fal, fbh[ni2], accc[mi2][ni2]);
            }
            __builtin_amdgcn_s_setprio(0);
        }
    }

    const int wr = (w >> 1) * 64;
    const int wc = (w & 1) * 64;
#pragma unroll
    for (int mi2 = 0; mi2 < 4; ++mi2) {
        int row = m0 + wr + mi2 * 16 + lg * 4;
#pragma unroll
        for (int ni2 = 0; ni2 < 4; ++ni2) {
            int col = n0 + wc + ni2 * 16 + l15;
            float bv = bias[col];
#pragma unroll
            for (int j = 0; j < 4; ++j) {
                float val = accm[mi2][ni2][j] + accc[mi2][ni2][j] * INV_LO_SCALE + bv;
                epi_write<EPI>(val, row + j, col, N, C, Oh, Ol, X2h, X2l, X3h, X3l);
            }
        }
    }
}

template<int EPI>
__global__ __launch_bounds__(256, 2)
void gemm128(const f16* __restrict__ Ah, const f16* __restrict__ Al,
             const f16* __restrict__ Bh, const f16* __restrict__ Bl,
             const float* __restrict__ bias, float* __restrict__ C,
             f16* __restrict__ Oh, f16* __restrict__ Ol,
             f16* __restrict__ X2h, f16* __restrict__ X2l,
             f16* __restrict__ X3h, f16* __restrict__ X3l, int K, int N)
{
    __shared__ f16 smem[2][16384];

    int mi, ni;
    swz_decode(mi, ni);
    const int m0 = mi * 128;
    const int n0 = ni * 128;

    const int tid = threadIdx.x;
    const int lane = tid & 63;
    const int w = tid >> 6;
    const int l15 = lane & 15;
    const int lg = lane >> 4;

    f32x4 accm[4][4];
    f32x4 accc[4][4];
#pragma unroll
    for (int i = 0; i < 4; ++i)
#pragma unroll
        for (int j = 0; j < 4; ++j) {
            accm[i][j] = (f32x4){0.f, 0.f, 0.f, 0.f};
            accc[i][j] = (f32x4){0.f, 0.f, 0.f, 0.f};
        }

    const f16* gA0 = Ah + (size_t)(m0 + w * 32 + l15) * K + lg * 8;
    const f16* gA1 = gA0 + 16 * (size_t)K;
    const f16* gAl0 = Al + (size_t)(m0 + w * 32 + l15) * K + lg * 8;
    const f16* gAl1 = gAl0 + 16 * (size_t)K;
    const f16* gB0 = Bh + (size_t)(n0 + w * 32 + l15) * K + lg * 8;
    const f16* gB1 = gB0 + 16 * (size_t)K;
    const f16* gBl0 = Bl + (size_t)(n0 + w * 32 + l15) * K + lg * 8;
    const f16* gBl1 = gBl0 + 16 * (size_t)K;
    const int ldsb0 = w * 1024;
    const int ldsb1 = w * 1024 + 512;

    const int nt = K >> 5;

#define STAGE(buf, k0)                                   \
    {                                                    \
        f16* sb = &smem[buf][0];                         \
        GLOAD16(gA0 + (k0), sb + ldsb0);                 \
        GLOAD16(gA1 + (k0), sb + ldsb1);                 \
        GLOAD16(gAl0 + (k0), sb + 4096 + ldsb0);         \
        GLOAD16(gAl1 + (k0), sb + 4096 + ldsb1);         \
        GLOAD16(gB0 + (k0), sb + 8192 + ldsb0);          \
        GLOAD16(gB1 + (k0), sb + 8192 + ldsb1);          \
        GLOAD16(gBl0 + (k0), sb + 12288 + ldsb0);        \
        GLOAD16(gBl1 + (k0), sb + 12288 + ldsb1);        \
    }

    STAGE(0, 0);
    __syncthreads();

    const int fro = lg * 128 + l15 * 8;
    const int wrg = (w >> 1) * 4;
    const int wcg = (w & 1) * 4;

    int cur = 0;
    for (int t = 0; t < nt; ++t) {
        if (t + 1 < nt) STAGE(cur ^ 1, (t + 1) * 32);

        const f16* sb = &smem[cur][0];
        f16x8 fbh[4], fbl[4];
#pragma unroll
        for (int ni2 = 0; ni2 < 4; ++ni2) {
            int offb = 8192 + (wcg + ni2) * 512 + fro;
            fbh[ni2] = *(const f16x8*)(sb + offb);
            fbl[ni2] = *(const f16x8*)(sb + offb + 4096);
        }
#pragma unroll
        for (int mi2 = 0; mi2 < 4; ++mi2) {
            int offa = (wrg + mi2) * 512 + fro;
            f16x8 fah = *(const f16x8*)(sb + offa);
            f16x8 fal = *(const f16x8*)(sb + offa + 4096);
            __builtin_amdgcn_s_setprio(1);
#pragma unroll
            for (int ni2 = 0; ni2 < 4; ++ni2) {
                accm[mi2][ni2] = MFMA16(fah, fbh[ni2], accm[mi2][ni2]);
                accc[mi2][ni2] = MFMA16(fah, fbl[ni2], accc[mi2][ni2]);
                accc[mi2][ni2] = MFMA16(fal, fbh[ni2], accc[mi2][ni2]);
            }
            __builtin_amdgcn_s_setprio(0);
        }

        __syncthreads();
        cur ^= 1;
    }
#undef STAGE

    const int wr = (w >> 1) * 64;
    const int wc = (w & 1) * 64;
#pragma unroll
    for (int mi2 = 0; mi2 < 4; ++mi2) {
        int row = m0 + wr + mi2 * 16 + lg * 4;
#pragma unroll
        for (int ni2 = 0; ni2 < 4; ++ni2) {
            int col = n0 + wc + ni2 * 16 + l15;
            float bv = bias[col];
#pragma unroll
            for (int j = 0; j < 4; ++j) {
                float val = accm[mi2][ni2][j] + accc[mi2][ni2][j] * INV_LO_SCALE + bv;
                epi_write<EPI>(val, row + j, col, N, C, Oh, Ol, X2h, X2l, X3h, X3l);
            }
        }
    }
}

// ---------------------------------------------------------------------------
// MFMA attention (V arrives [bh][l][d]; transpose during LDS staging).
// ---------------------------------------------------------------------------
__global__ __launch_bounds__(256, 1)
void attn_mfma_kernel(const f16* __restrict__ Qh, const f16* __restrict__ Ql,
                      const f16* __restrict__ Kh, const f16* __restrict__ Kl,
                      const f16* __restrict__ Vh, const f16* __restrict__ Vl,
                      f16* __restrict__ ch, f16* __restrict__ cl)
{
    __shared__ f16 sKh[256 * 72];
    __shared__ f16 sKl[256 * 72];
    __shared__ f16 sVh[64 * 264];
    __shared__ f16 sVl[64 * 264];
    __shared__ f16 sPh[4][1280];
    __shared__ f16 sPl[4][1280];

    const int bh = blockIdx.x >> 1;
    const int qbase = (blockIdx.x & 1) * 128;
    const int b = bh / 12;
    const int h = bh % 12;
    const int tid = threadIdx.x;
    const int w = tid >> 6;
    const int l = tid & 63;
    const int l15 = l & 15;
    const int lg = l >> 4;

    {
        const f16* gKh = Kh + (size_t)bh * 16384;
        const f16* gKl = Kl + (size_t)bh * 16384;
#pragma unroll
        for (int i = 0; i < 8; ++i) {
            int c = tid + i * 256;
            int off = (c >> 3) * 72 + (c & 7) * 8;
            *(f16x8*)(sKh + off) = *(const f16x8*)(gKh + c * 8);
            *(f16x8*)(sKl + off) = *(const f16x8*)(gKl + c * 8);
        }
        const f16* gVh = Vh + (size_t)bh * 16384;
        const f16* gVl = Vl + (size_t)bh * 16384;
#pragma unroll
        for (int i = 0; i < 8; ++i) {
            int c = tid + i * 256;
            int l2 = c >> 3;
            int d0 = (c & 7) * 8;
            f16x8 vh = *(const f16x8*)(gVh + l2 * 64 + d0);
            f16x8 vl = *(const f16x8*)(gVl + l2 * 64 + d0);
#pragma unroll
            for (int j = 0; j < 8; ++j) {
                sVh[(d0 + j) * 264 + l2] = vh[j];
                sVl[(d0 + j) * 264 + l2] = vl[j];
            }
        }
    }
    __syncthreads();

    f16x8 qfh[2][2], qfl[2][2];
#pragma unroll
    for (int mt = 0; mt < 2; ++mt) {
        int qr = qbase + w * 32 + mt * 16 + l15;
        size_t qo = ((size_t)bh * 256 + qr) * 64 + lg * 8;
        qfh[mt][0] = *(const f16x8*)(Qh + qo);
        qfh[mt][1] = *(const f16x8*)(Qh + qo + 32);
        qfl[mt][0] = *(const f16x8*)(Ql + qo);
        qfl[mt][1] = *(const f16x8*)(Ql + qo + 32);
    }

    f32x4 S[2][16];
#pragma unroll
    for (int nt = 0; nt < 16; ++nt) {
        int kr = nt * 16 + l15;
        int kaddr = kr * 72 + lg * 8;
        f16x8 kh0 = *(const f16x8*)(sKh + kaddr);
        f16x8 kh1 = *(const f16x8*)(sKh + kaddr + 32);
        f16x8 kl0 = *(const f16x8*)(sKl + kaddr);
        f16x8 kl1 = *(const f16x8*)(sKl + kaddr + 32);
#pragma unroll
        for (int mt = 0; mt < 2; ++mt) {
            f32x4 am = (f32x4){0.f, 0.f, 0.f, 0.f};
            f32x4 ac = (f32x4){0.f, 0.f, 0.f, 0.f};
            am = MFMA16(qfh[mt][0], kh0, am);
            am = MFMA16(qfh[mt][1], kh1, am);
            ac = MFMA16(qfh[mt][0], kl0, ac);
            ac = MFMA16(qfh[mt][1], kl1, ac);
            ac = MFMA16(qfl[mt][0], kh0, ac);
            ac = MFMA16(qfl[mt][1], kh1, ac);
            S[mt][nt] = (am + ac * INV_LO_SCALE) * 0.125f;
        }
    }

#pragma unroll
    for (int mt = 0; mt < 2; ++mt)
#pragma unroll
        for (int j = 0; j < 4; ++j) {
            float m = S[mt][0][j];
#pragma unroll
            for (int nt = 1; nt < 16; ++nt) m = fmaxf(m, S[mt][nt][j]);
            m = fmaxf(m, __shfl_xor(m, 1));
            m = fmaxf(m, __shfl_xor(m, 2));
            m = fmaxf(m, __shfl_xor(m, 4));
            m = fmaxf(m, __shfl_xor(m, 8));
            float s = 0.f;
#pragma unroll
            for (int nt = 0; nt < 16; ++nt) {
                float e = fexp2((S[mt][nt][j] - m) * LOG2E);
                S[mt][nt][j] = e;
                s += e;
            }
            s += __shfl_xor(s, 1);
            s += __shfl_xor(s, 2);
            s += __shfl_xor(s, 4);
            s += __shfl_xor(s, 8);
            float inv = 1.0f / s;
#pragma unroll
            for (int nt = 0; nt < 16; ++nt) S[mt][nt][j] *= inv;
        }

    f32x4 Ohh[2][4], Occ[2][4];
#pragma unroll
    for (int mt = 0; mt < 2; ++mt)
#pragma unroll
        for (int dt = 0; dt < 4; ++dt) {
            Ohh[mt][dt] = (f32x4){0.f, 0.f, 0.f, 0.f};
            Occ[mt][dt] = (f32x4){0.f, 0.f, 0.f, 0.f};
        }

    f16* pbh = &sPh[w][0];
    f16* pbl = &sPl[w][0];
#pragma unroll
    for (int kp = 0; kp < 8; ++kp) {
#pragma unroll
        for (int mt = 0; mt < 2; ++mt)
#pragma unroll
            for (int n2 = 0; n2 < 2; ++n2) {
                int nt = kp * 2 + n2;
#pragma unroll
                for (int j = 0; j < 4; ++j) {
                    int prow = mt * 16 + lg * 4 + j;
                    int pcol = n2 * 16 + l15;
                    f16 hi, lo;
                    split1(S[mt][nt][j], hi, lo);
                    pbh[prow * 40 + pcol] = hi;
                    pbl[prow * 40 + pcol] = lo;
                }
            }
        __builtin_amdgcn_wave_barrier();
#pragma unroll
        for (int mt = 0; mt < 2; ++mt) {
            int paddr = (mt * 16 + l15) * 40 + lg * 8;
            f16x8 ph = *(const f16x8*)(pbh + paddr);
            f16x8 pl = *(const f16x8*)(pbl + paddr);
#pragma unroll
            for (int dt = 0; dt < 4; ++dt) {
                int vaddr = (dt * 16 + l15) * 264 + kp * 32 + lg * 8;
                f16x8 vh = *(const f16x8*)(sVh + vaddr);
                f16x8 vl = *(const f16x8*)(sVl + vaddr);
                Ohh[mt][dt] = MFMA16(ph, vh, Ohh[mt][dt]);
                Occ[mt][dt] = MFMA16(ph, vl, Occ[mt][dt]);
                Occ[mt][dt] = MFMA16(pl, vh, Occ[mt][dt]);
            }
        }
        __builtin_amdgcn_wave_barrier();
    }

#pragma unroll
    for (int mt = 0; mt < 2; ++mt)
#pragma unroll
        for (int dt = 0; dt < 4; ++dt) {
            f32x4 o = Ohh[mt][dt] + Occ[mt][dt] * INV_LO_SCALE;
#pragma unroll
            for (int j = 0; j < 4; ++j) {
                int q = qbase + w * 32 + mt * 16 + lg * 4 + j;
                int d = dt * 16 + l15;
                size_t off = ((size_t)(b * 256 + q)) * 768 + h * 64 + d;
                f16 hi, lo;
                split1(o[j], hi, lo);
                ch[off] = hi;
                cl[off] = lo;
            }
        }
}

// ---------------------------------------------------------------------------
// Transpose+split, 64x64 tiles, 16 outputs/thread, f16x8 (16B) stores.
// ---------------------------------------------------------------------------
__device__ __forceinline__ void tsplit64_tile(const float* __restrict__ W,
                                              f16* __restrict__ Th, f16* __restrict__ Tl,
                                              int K, int N, int kb, int nb, int tid,
                                              float (*tile)[65])
{
    const int k0 = kb * 64;
    const int n0 = nb * 64;
    const int r = tid >> 2;
    const int c16 = (tid & 3) * 16;
#pragma unroll
    for (int j = 0; j < 16; j += 4) {
        float4 v = *(const float4*)&W[(size_t)(k0 + r) * N + n0 + c16 + j];
        tile[r][c16 + j + 0] = v.x;
        tile[r][c16 + j + 1] = v.y;
        tile[r][c16 + j + 2] = v.z;
        tile[r][c16 + j + 3] = v.w;
    }
    __syncthreads();
    const int n = tid >> 2;
    const int k16 = (tid & 3) * 16;
    f16 hs[16], ls[16];
#pragma unroll
    for (int j = 0; j < 16; ++j) split1(tile[k16 + j][n], hs[j], ls[j]);
    size_t o = (size_t)(n0 + n) * K + k0 + k16;
    *(f16x8*)(Th + o)     = (f16x8){hs[0], hs[1], hs[2], hs[3], hs[4], hs[5], hs[6], hs[7]};
    *(f16x8*)(Th + o + 8) = (f16x8){hs[8], hs[9], hs[10], hs[11], hs[12], hs[13], hs[14], hs[15]};
    *(f16x8*)(Tl + o)     = (f16x8){ls[0], ls[1], ls[2], ls[3], ls[4], ls[5], ls[6], ls[7]};
    *(f16x8*)(Tl + o + 8) = (f16x8){ls[8], ls[9], ls[10], ls[11], ls[12], ls[13], ls[14], ls[15]};
}

// per-layer split-weight element offsets (f16 units)
#define OFF_QKV_H 0
#define OFF_QKV_L 1769472
#define OFF_WO_H  3538944
#define OFF_WO_L  4128768
#define OFF_W1_H  4718592
#define OFF_W1_L  7077888
#define OFF_W2_H  9437184
#define OFF_W2_L  11796480
#define WL_STRIDE 14155776   // f16 elems per layer (28.3 MB)

__global__ void tsplit_all_kernel(const float* __restrict__ Wq, const float* __restrict__ Wk,
                                  const float* __restrict__ Wv, const float* __restrict__ Wo,
                                  const float* __restrict__ W1, const float* __restrict__ W2,
                                  f16* __restrict__ wout, size_t outStride)
{
    __shared__ float tile[64][65];
    const int tid = threadIdx.x;
    const int layer = blockIdx.y;
    const size_t o768 = (size_t)layer * 589824;
    const size_t o3072 = (size_t)layer * 2359296;
    f16* base = wout + (size_t)layer * outStride;
    int bid = blockIdx.x;
    if (bid < 144) {
        tsplit64_tile(Wq + o768, base + OFF_QKV_H, base + OFF_QKV_L,
                      768, 768, bid % 12, bid / 12, tid, tile);
    } else if (bid < 288) {
        bid -= 144;
        tsplit64_tile(Wk + o768, base + OFF_QKV_H + 768 * 768, base + OFF_QKV_L + 768 * 768,
                      768, 768, bid % 12, bid / 12, tid, tile);
    } else if (bid < 432) {
        bid -= 288;
        tsplit64_tile(Wv + o768, base + OFF_QKV_H + 2 * 768 * 768, base + OFF_QKV_L + 2 * 768 * 768,
                      768, 768, bid % 12, bid / 12, tid, tile);
    } else if (bid < 576) {
        bid -= 432;
        tsplit64_tile(Wo + o768, base + OFF_WO_H, base + OFF_WO_L,
                      768, 768, bid % 12, bid / 12, tid, tile);
    } else if (bid < 1152) {
        bid -= 576;
        tsplit64_tile(W1 + o3072, base + OFF_W1_H, base + OFF_W1_L,
                      768, 3072, bid % 12, bid / 12, tid, tile);
    } else {
        bid -= 1152;
        tsplit64_tile(W2 + o3072, base + OFF_W2_H, base + OFF_W2_L,
                      3072, 768, bid % 48, bid / 48, tid, tile);
    }
}

__global__ void pack_qkv_bias_kernel(const float* __restrict__ bq, const float* __restrict__ bk,
                                     const float* __restrict__ bv, float* __restrict__ qkvb)
{
    const int i = blockIdx.x;
    const int tid = threadIdx.x;
    for (int c = tid; c < 768; c += 256) {
        qkvb[i * 2304 + c]        = bq[i * 768 + c];
        qkvb[i * 2304 + 768 + c]  = bk[i * 768 + c];
        qkvb[i * 2304 + 1536 + c] = bv[i * 768 + c];
    }
}

// ---------------------------------------------------------------------------
// Wave-per-token LayerNorm: zero barriers, vector IO.
// ---------------------------------------------------------------------------
__device__ __forceinline__ void ln_wave_core(float v[12], const float* __restrict__ g,
                                             const float* __restrict__ be,
                                             float* __restrict__ x,
                                             f16* __restrict__ xh, f16* __restrict__ xl,
                                             size_t base, int cb)
{
    float s = 0.f;
#pragma unroll
    for (int j = 0; j < 12; ++j) s += v[j];
#pragma unroll
    for (int off = 32; off > 0; off >>= 1) s += __shfl_xor(s, off);
    const float mu = s * (1.0f / 768.0f);
    float d2 = 0.f;
#pragma unroll
    for (int j = 0; j < 12; ++j) { float d = v[j] - mu; d2 += d * d; }
#pragma unroll
    for (int off = 32; off > 0; off >>= 1) d2 += __shfl_xor(d2, off);
    const float rstd = 1.0f / sqrtf(d2 * (1.0f / 768.0f) + 1e-12f);

    const float4* ga = (const float4*)(g + cb);
    const float4* ba = (const float4*)(be + cb);
    float o[12];
#pragma unroll
    for (int j = 0; j < 3; ++j) {
        float4 gg = ga[j];
        float4 bb = ba[j];
        o[j * 4 + 0] = (v[j * 4 + 0] - mu) * rstd * gg.x + bb.x;
        o[j * 4 + 1] = (v[j * 4 + 1] - mu) * rstd * gg.y + bb.y;
        o[j * 4 + 2] = (v[j * 4 + 2] - mu) * rstd * gg.z + bb.z;
        o[j * 4 + 3] = (v[j * 4 + 3] - mu) * rstd * gg.w + bb.w;
    }
    float4* xo = (float4*)(x + base);
#pragma unroll
    for (int j = 0; j < 3; ++j)
        xo[j] = (float4){o[j * 4 + 0], o[j * 4 + 1], o[j * 4 + 2], o[j * 4 + 3]};

    f16 ho[12], lo[12];
#pragma unroll
    for (int j = 0; j < 12; ++j) split1(o[j], ho[j], lo[j]);
#pragma unroll
    for (int j = 0; j < 3; ++j) {
        *(f16x4*)(xh + base + j * 4) = (f16x4){ho[j * 4], ho[j * 4 + 1], ho[j * 4 + 2], ho[j * 4 + 3]};
        *(f16x4*)(xl + base + j * 4) = (f16x4){lo[j * 4], lo[j * 4 + 1], lo[j * 4 + 2], lo[j * 4 + 3]};
    }
}

__global__ __launch_bounds__(256)
void res_ln_w(float* __restrict__ x, const float* __restrict__ y,
              const float* __restrict__ g, const float* __restrict__ be,
              f16* __restrict__ xh, f16* __restrict__ xl)
{
    const int tok = blockIdx.x * 4 + (threadIdx.x >> 6);
    const int cb = (threadIdx.x & 63) * 12;
    const size_t base = (size_t)tok * 768 + cb;
    const float4* xa = (const float4*)(x + base);
    const float4* ya = (const float4*)(y + base);
    float v[12];
#pragma unroll
    for (int j = 0; j < 3; ++j) {
        float4 a = xa[j];
        float4 b2 = ya[j];
        v[j * 4 + 0] = a.x + b2.x;
        v[j * 4 + 1] = a.y + b2.y;
        v[j * 4 + 2] = a.z + b2.z;
        v[j * 4 + 3] = a.w + b2.w;
    }
    ln_wave_core(v, g, be, x, xh, xl, base, cb);
}

__global__ __launch_bounds__(256)
void embed_ln_w(const int* __restrict__ datas, const float* __restrict__ wemb,
                const float* __restrict__ pemb, const float* __restrict__ temb,
                const float* __restrict__ g, const float* __restrict__ be,
                float* __restrict__ x, f16* __restrict__ xh, f16* __restrict__ xl)
{
    const int tok = blockIdx.x * 4 + (threadIdx.x >> 6);
    const int cb = (threadIdx.x & 63) * 12;
    const size_t base = (size_t)tok * 768 + cb;
    const int widx = datas[tok];
    const int l = tok & 255;
    const float4* wa = (const float4*)(wemb + (size_t)widx * 768 + cb);
    const float4* pa = (const float4*)(pemb + (size_t)l * 768 + cb);
    const float4* ta = (const float4*)(temb + cb);
    float v[12];
#pragma unroll
    for (int j = 0; j < 3; ++j) {
        float4 a = wa[j];
        float4 b2 = pa[j];
        float4 c2 = ta[j];
        v[j * 4 + 0] = a.x + b2.x + c2.x;
        v[j * 4 + 1] = a.y + b2.y + c2.y;
        v[j * 4 + 2] = a.z + b2.z + c2.z;
        v[j * 4 + 3] = a.w + b2.w + c2.w;
    }
    ln_wave_core(v, g, be, x, xh, xl, base, cb);
}

// ---------------------------------------------------------------------------
// CRF heads + scans + loss (unchanged)
// ---------------------------------------------------------------------------
__global__ void head_kernel(const float* __restrict__ X, const float* __restrict__ Wh,
                            const float* __restrict__ bh, float* __restrict__ out, int T)
{
    __shared__ float xs[768];
    __shared__ double part[8][32];
    const int i = blockIdx.x;
    const int tid = threadIdx.x;
    for (int c = tid; c < 768; c += 256) xs[c] = X[(size_t)i * 768 + c];
    __syncthreads();
    const int p = tid >> 5;
    const int tg = tid & 31;
    if (tg < T) {
        double a = 0;
        for (int d = p * 96; d < p * 96 + 96; ++d)
            a += (double)xs[d] * (double)Wh[d * T + tg];
        part[p][tg] = a;
    }
    __syncthreads();
    if (tid < T) {
        double s = 0;
        for (int pp = 0; pp < 8; ++pp) s += part[pp][tid];
        out[(size_t)i * T + tid] = (float)(s + (double)bh[tid]);
    }
}

__global__ void crf_num_kernel(const float* __restrict__ em, const int* __restrict__ labels,
                               const float* __restrict__ start, const float* __restrict__ endv,
                               const float* __restrict__ trans, float* __restrict__ num, int T)
{
    __shared__ double red[256];
    const int b = blockIdx.x;
    const int tid = threadIdx.x;
    const int tag = labels[b * 256 + tid];
    float v;
    if (tid == 0) {
        v = start[tag] + em[(size_t)(b * 256) * T + tag];
    } else {
        int pt = labels[b * 256 + tid - 1];
        v = trans[pt * T + tag] + em[(size_t)(b * 256 + tid) * T + tag];
    }
    red[tid] = (double)v;
    __syncthreads();
    for (int st = 128; st > 0; st >>= 1) { if (tid < st) red[tid] += red[tid + st]; __syncthreads(); }
    if (tid == 0) num[b] = (float)(red[0] + (double)endv[labels[b * 256 + 255]]);
}

template<int T>
__global__ void crf_scan_kernel(const float* __restrict__ emG, const float* __restrict__ start,
                                const float* __restrict__ endv, const float* __restrict__ trans,
                                float* __restrict__ den, float* __restrict__ tagOut)
{
    __shared__ float ems[256 * T];
    __shared__ float albuf[32];
    __shared__ unsigned char hist[255 * T + 1];
    const int b = blockIdx.x;
    const bool vit = (blockIdx.y == 1);
    const int c = threadIdx.x;

    for (int idx = c; idx < 256 * T; idx += 64)
        ems[idx] = emG[(size_t)b * 256 * T + idx];
    float trc[T];
#pragma unroll
    for (int p = 0; p < T; ++p) trc[p] = (c < T) ? trans[p * T + c] : 0.f;
    const float ec = (c < T) ? endv[c] : -1e30f;
    __syncthreads();

    float alpha = (c < T) ? (start[c] + ems[c]) : -1e30f;

    if (!vit) {
        for (int t = 1; t < 256; ++t) {
            if (c < T) albuf[c] = alpha;
            __builtin_amdgcn_wave_barrier();
            float a[T];
            float m = -1e30f;
#pragma unroll
            for (int p = 0; p < T; ++p) { a[p] = albuf[p] + trc[p]; m = fmaxf(m, a[p]); }
            float s = 0.f;
#pragma unroll
            for (int p = 0; p < T; ++p) s += fexp2((a[p] - m) * LOG2E);
            float na = m + flog2(s) * 0.6931471805599453f + ems[t * T + c];
            __builtin_amdgcn_wave_barrier();
            if (c < T) alpha = na;
        }
        if (c < T) albuf[c] = alpha + ec;
        __builtin_amdgcn_wave_barrier();
        if (c == 0) {
            float m = -1e30f;
            for (int p = 0; p < T; ++p) m = fmaxf(m, albuf[p]);
            float s = 0.f;
            for (int p = 0; p < T; ++p) s += fexp2((albuf[p] - m) * LOG2E);
            den[b] = m + flog2(s) * 0.6931471805599453f;
        }
    } else {
        for (int t = 1; t < 256; ++t) {
            if (c < T) albuf[c] = alpha;
            __builtin_amdgcn_wave_barrier();
            float best = albuf[0] + trc[0];
            int arg = 0;
#pragma unroll
            for (int p = 1; p < T; ++p) {
                float v2 = albuf[p] + trc[p];
                if (v2 > best) { best = v2; arg = p; }
            }
            __builtin_amdgcn_wave_barrier();
            if (c < T) {
                alpha = best + ems[t * T + c];
                hist[(t - 1) * T + c] = (unsigned char)arg;
            }
        }
        if (c < T) albuf[c] = alpha + ec;
        __builtin_amdgcn_wave_barrier();
        if (c == 0) {
            float bv = albuf[0];
            int cur = 0;
            for (int p = 1; p < T; ++p) {
                if (albuf[p] > bv) { bv = albuf[p]; cur = p; }
            }
            tagOut[b * 256 + 255] = (float)cur;
            for (int t = 254; t >= 0; --t) {
                cur = hist[t * T + cur];
                tagOut[b * 256 + t] = (float)cur;
            }
        }
    }
}

__global__ void loss_kernel(const float* __restrict__ num, const float* __restrict__ den,
                            float* __restrict__ out)
{
    __shared__ double red[32];
    const int tid = threadIdx.x;
    red[tid] = (double)num[tid] - (double)den[tid];
    __syncthreads();
    for (int st = 16; st > 0; st >>= 1) { if (tid < st) red[tid] += red[tid + st]; __syncthreads(); }
    if (tid == 0) out[0] = (float)(-red[0]);
}

// ---------------------------------------------------------------------------
extern "C" void kernel_launch(void* const* d_in, const int* in_sizes, int n_in,
                              void* d_out, int out_size, void* d_ws, size_t ws_size,
                              hipStream_t stream)
{
    (void)in_sizes; (void)n_in; (void)out_size;
    const int* datas       = (const int*)d_in[0];
    const int* ele_labels  = (const int*)d_in[1];
    const int* role_labels = (const int*)d_in[2];
    // d_in[3] seq_mask: all ones
    const float* word_emb = (const float*)d_in[4];
    const float* pos_emb  = (const float*)d_in[5];
    const float* type_emb = (const float*)d_in[6];
    const float* emb_g = (const float*)d_in[7];
    const float* emb_b = (const float*)d_in[8];
    const float* Wq = (const float*)d_in[9];  const float* bq = (const float*)d_in[10];
    const float* Wk = (const float*)d_in[11]; const float* bk = (const float*)d_in[12];
    const float* Wv = (const float*)d_in[13]; const float* bv = (const float*)d_in[14];
    const float* Wo = (const float*)d_in[15]; const float* bo = (const float*)d_in[16];
    const float* ln1g = (const float*)d_in[17]; const float* ln1b = (const float*)d_in[18];
    const float* W1 = (const float*)d_in[19]; const float* b1 = (const float*)d_in[20];
    const float* W2 = (const float*)d_in[21]; const float* b2 = (const float*)d_in[22];
    const float* ln2g = (const float*)d_in[23]; const float* ln2b = (const float*)d_in[24];
    const float* W_ele = (const float*)d_in[25]; const float* b_ele = (const float*)d_in[26];
    const float* W_role = (const float*)d_in[27]; const float* b_role = (const float*)d_in[28];
    const float* ele_start = (const float*)d_in[29];
    const float* ele_end   = (const float*)d_in[30];
    const float* ele_trans = (const float*)d_in[31];
    const float* role_start = (const float*)d_in[32];
    const float* role_end   = (const float*)d_in[33];
    const float* role_trans = (const float*)d_in[34];
    float* out = (float*)d_out;

    uint8_t* ws = (uint8_t*)d_ws;
    float* x      = (float*)(ws + 0x0000000);   // 4096x768 f32
    f16* xh       = (f16*)  (ws + 0x0C00000);
    f16* xl       = (f16*)  (ws + 0x1200000);
    f16* Qh       = (f16*)  (ws + 0x1800000);   // [b,h,l,d] f16
    f16* Ql       = (f16*)  (ws + 0x1E00000);
    f16* Kh       = (f16*)  (ws + 0x2400000);
    f16* Kl       = (f16*)  (ws + 0x2A00000);
    f16* Vh       = (f16*)  (ws + 0x3000000);   // [b,h,l,d] f16 (attn transposes)
    f16* Vl       = (f16*)  (ws + 0x3600000);
    f16* ctxh     = (f16*)  (ws + 0x3C00000);   // [token][768]
    f16* ctxl     = (f16*)  (ws + 0x4200000);
    float* rbuf   = (float*)(ws + 0x4800000);   // 4096x768 f32 (ends 0x5400000)
    f16* hh       = (f16*)  (ws + 0x1800000);   // 4096x3072 (over Qh..Kl)
    f16* hl       = (f16*)  (ws + 0x3000000);   // (over Vh..ctxl)
    float* qkvb   = (float*)(ws + 0x5400000);   // 12x2304
    float* ele_em = (float*)(ws + 0x5420000);   // 4096x17
    float* role_em= (float*)(ws + 0x5468000);   // 4096x7
    float* numb   = (float*)(ws + 0x5484000);   // [32]
    float* denb   = (float*)(ws + 0x5484100);   // [32]
    f16* wsplit   = (f16*)  (ws + 0x5490000);   // split weights: 1 or 12 layers

    const bool hoist = ws_size >= (0x5490000ull + 12ull * WL_STRIDE * 2ull + 0x10000ull);

    pack_qkv_bias_kernel<<<12, 256, 0, stream>>>(bq, bk, bv, qkvb);
    embed_ln_w<<<1024, 256, 0, stream>>>(datas, word_emb, pos_emb, type_emb,
                                         emb_g, emb_b, x, xh, xl);
    if (hoist)
        tsplit_all_kernel<<<dim3(1728, 12), 256, 0, stream>>>(Wq, Wk, Wv, Wo, W1, W2,
                                                              wsplit, WL_STRIDE);

    for (int i = 0; i < 12; ++i) {
        if (!hoist)
            tsplit_all_kernel<<<dim3(1728, 1), 256, 0, stream>>>(
                Wq + (size_t)i * 589824, Wk + (size_t)i * 589824,
                Wv + (size_t)i * 589824, Wo + (size_t)i * 589824,
                W1 + (size_t)i * 2359296, W2 + (size_t)i * 2359296,
                wsplit, 0);
        f16* wl = wsplit + (hoist ? (size_t)i * WL_STRIDE : 0);

        // QKV fused: [4096x768] @ [768x2304] -> split f16 Q/K/V head-major
        gemm128s<2><<<dim3(32, 18), 256, 0, stream>>>(xh, xl, wl + OFF_QKV_H, wl + OFF_QKV_L,
                                                      qkvb + i * 2304, nullptr,
                                                      Qh, Ql, Kh, Kl, Vh, Vl, 768, 2304);
        attn_mfma_kernel<<<384, 256, 0, stream>>>(Qh, Ql, Kh, Kl, Vh, Vl, ctxh, ctxl);
        gemm128<0><<<dim3(32, 6), 256, 0, stream>>>(ctxh, ctxl, wl + OFF_WO_H, wl + OFF_WO_L,
                                                    bo + i * 768, rbuf, nullptr, nullptr,
                                                    nullptr, nullptr, nullptr, nullptr, 768, 768);
        res_ln_w<<<1024, 256, 0, stream>>>(x, rbuf, ln1g + i * 768, ln1b + i * 768, xh, xl);
        // FF1 with fused GELU+split epilogue
        gemm128s<1><<<dim3(32, 24), 256, 0, stream>>>(xh, xl, wl + OFF_W1_H, wl + OFF_W1_L,
                                                      b1 + i * 3072, nullptr, hh, hl,
                                                      nullptr, nullptr, nullptr, nullptr, 768, 3072);
        gemm128<0><<<dim3(32, 6), 256, 0, stream>>>(hh, hl, wl + OFF_W2_H, wl + OFF_W2_L,
                                                    b2 + i * 768, rbuf, nullptr, nullptr,
                                                    nullptr, nullptr, nullptr, nullptr, 3072, 768);
        res_ln_w<<<1024, 256, 0, stream>>>(x, rbuf, ln2g + i * 768, ln2b + i * 768, xh, xl);
    }

    head_kernel<<<4096, 256, 0, stream>>>(x, W_ele, b_ele, ele_em, 17);
    head_kernel<<<4096, 256, 0, stream>>>(x, W_role, b_role, role_em, 7);

    crf_num_kernel<<<16, 256, 0, stream>>>(ele_em, ele_labels, ele_start, ele_end, ele_trans, numb, 17);
    crf_num_kernel<<<16, 256, 0, stream>>>(role_em, role_labels, role_start, role_end, role_trans, numb + 16, 7);
    crf_scan_kernel<17><<<dim3(16, 2), 64, 0, stream>>>(ele_em, ele_start, ele_end, ele_trans, denb, out + 1);
    crf_scan_kernel<7><<<dim3(16, 2), 64, 0, stream>>>(role_em, role_start, role_end, role_trans, denb + 16, out + 1 + 4096);
    loss_kernel<<<1, 32, 0, stream>>>(numb, denb, out);
}

// Round 14
// 5197.562 us; speedup vs baseline: 2.3461x; 2.3461x over previous
//
#include <hip/hip_runtime.h>
#include <stdint.h>
#include <math.h>

typedef _Float16 f16;
typedef _Float16 f16x4 __attribute__((ext_vector_type(4)));
typedef _Float16 f16x8 __attribute__((ext_vector_type(8)));
typedef float f32x4 __attribute__((ext_vector_type(4)));

#define LO_SCALE 2048.0f
#define INV_LO_SCALE (1.0f/2048.0f)
#define LOG2E 1.4426950408889634f
#define MFMA16(a, b, c) __builtin_amdgcn_mfma_f32_16x16x32_f16(a, b, c, 0, 0, 0)

__device__ __forceinline__ void split1(float x, f16 &hi, f16 &lo) {
    f16 h = (f16)x;
    hi = h;
    lo = (f16)((x - (float)h) * LO_SCALE);
}

__device__ __forceinline__ float fexp2(float x) {
#if __has_builtin(__builtin_amdgcn_exp2f)
    return __builtin_amdgcn_exp2f(x);
#else
    return exp2f(x);
#endif
}
__device__ __forceinline__ float flog2(float x) {
#if __has_builtin(__builtin_amdgcn_logf)
    return __builtin_amdgcn_logf(x);
#else
    return log2f(x);
#endif
}

#define GLOAD16(g, l) __builtin_amdgcn_global_load_lds( \
    (const __attribute__((address_space(1))) void*)(g), \
    (__attribute__((address_space(3))) void*)(l), 16, 0, 0)

// ---------------------------------------------------------------------------
// m-stripe XCD swizzle: chunk c = s&7 owns m-tiles [c*MT/8,(c+1)*MT/8),
// n iterates FASTEST within a chunk. Requires gridDim.x % 8 == 0.
// ---------------------------------------------------------------------------
__device__ __forceinline__ void swz_decode(int &mi, int &ni)
{
    const int NN = gridDim.y;
    int s = blockIdx.x + blockIdx.y * gridDim.x;
    const int c = s & 7;
    const int idx = s >> 3;
    const int mchunk = gridDim.x >> 3;
    const int md = idx / NN;
    mi = c * mchunk + md;
    ni = idx - md * NN;
}

// ---------------------------------------------------------------------------
// Epilogue writers. EPI2: Q,K,V all head-major [bh][lt][d].
// ---------------------------------------------------------------------------
template<int EPI>
__device__ __forceinline__ void epi_write(float val, int row, int col, int N,
                                          float* __restrict__ C,
                                          f16* __restrict__ Oh, f16* __restrict__ Ol,
                                          f16* __restrict__ X2h, f16* __restrict__ X2l,
                                          f16* __restrict__ X3h, f16* __restrict__ X3l)
{
    if constexpr (EPI == 0) {
        C[(size_t)row * N + col] = val;
    } else if constexpr (EPI == 1) {
        float ge = 0.5f * val * (1.0f + erff(val * 0.70710678118654752440f));
        f16 hi, lo;
        split1(ge, hi, lo);
        size_t o = (size_t)row * N + col;
        Oh[o] = hi;
        Ol[o] = lo;
    } else {
        int sect = col >= 1536 ? 2 : (col >= 768 ? 1 : 0);
        int cc = col - sect * 768;
        int hd = cc >> 6;
        int d = cc & 63;
        int bh = (row >> 8) * 12 + hd;
        int lt = row & 255;
        f16 hi, lo;
        split1(val, hi, lo);
        size_t o = ((size_t)bh * 256 + lt) * 64 + d;
        if (sect == 0)      { Oh[o] = hi;  Ol[o] = lo; }
        else if (sect == 1) { X2h[o] = hi; X2l[o] = lo; }
        else                { X3h[o] = hi; X3l[o] = lo; }
    }
}

// ---------------------------------------------------------------------------
// gemm128 (round-8/12 best config): 128x128 tile, 4 waves (2x2), per-wave
// 64x64 (acc = 128 VGPR -> hard cap 2 blocks/CU; do NOT raise launch_bounds:
// round-13 showed (256,4) spills acc to scratch, 2.3x total regression).
// BK=32, 2-phase dbuf global_load_lds staging, K-block-major LDS layout
// (0 bank conflicts verified), m-stripe XCD swizzle, setprio around MFMA.
// ---------------------------------------------------------------------------
template<int EPI>
__global__ __launch_bounds__(256, 2)
void gemm128(const f16* __restrict__ Ah, const f16* __restrict__ Al,
             const f16* __restrict__ Bh, const f16* __restrict__ Bl,
             const float* __restrict__ bias, float* __restrict__ C,
             f16* __restrict__ Oh, f16* __restrict__ Ol,
             f16* __restrict__ X2h, f16* __restrict__ X2l,
             f16* __restrict__ X3h, f16* __restrict__ X3l, int K, int N)
{
    __shared__ f16 smem[2][16384];   // [buf][arr(Ah,Al,Bh,Bl)][4096]

    int mi, ni;
    swz_decode(mi, ni);
    const int m0 = mi * 128;
    const int n0 = ni * 128;

    const int tid = threadIdx.x;
    const int lane = tid & 63;
    const int w = tid >> 6;
    const int l15 = lane & 15;
    const int lg = lane >> 4;

    f32x4 accm[4][4];
    f32x4 accc[4][4];
#pragma unroll
    for (int i = 0; i < 4; ++i)
#pragma unroll
        for (int j = 0; j < 4; ++j) {
            accm[i][j] = (f32x4){0.f, 0.f, 0.f, 0.f};
            accc[i][j] = (f32x4){0.f, 0.f, 0.f, 0.f};
        }

    const f16* gA0 = Ah + (size_t)(m0 + w * 32 + l15) * K + lg * 8;
    const f16* gA1 = gA0 + 16 * (size_t)K;
    const f16* gAl0 = Al + (size_t)(m0 + w * 32 + l15) * K + lg * 8;
    const f16* gAl1 = gAl0 + 16 * (size_t)K;
    const f16* gB0 = Bh + (size_t)(n0 + w * 32 + l15) * K + lg * 8;
    const f16* gB1 = gB0 + 16 * (size_t)K;
    const f16* gBl0 = Bl + (size_t)(n0 + w * 32 + l15) * K + lg * 8;
    const f16* gBl1 = gBl0 + 16 * (size_t)K;
    const int ldsb0 = w * 1024;
    const int ldsb1 = w * 1024 + 512;

    const int nt = K >> 5;

#define STAGE(buf, k0)                                   \
    {                                                    \
        f16* sb = &smem[buf][0];                         \
        GLOAD16(gA0 + (k0), sb + ldsb0);                 \
        GLOAD16(gA1 + (k0), sb + ldsb1);                 \
        GLOAD16(gAl0 + (k0), sb + 4096 + ldsb0);         \
        GLOAD16(gAl1 + (k0), sb + 4096 + ldsb1);         \
        GLOAD16(gB0 + (k0), sb + 8192 + ldsb0);          \
        GLOAD16(gB1 + (k0), sb + 8192 + ldsb1);          \
        GLOAD16(gBl0 + (k0), sb + 12288 + ldsb0);        \
        GLOAD16(gBl1 + (k0), sb + 12288 + ldsb1);        \
    }

    STAGE(0, 0);
    __syncthreads();

    const int fro = lg * 128 + l15 * 8;
    const int wrg = (w >> 1) * 4;
    const int wcg = (w & 1) * 4;

    int cur = 0;
    for (int t = 0; t < nt; ++t) {
        if (t + 1 < nt) STAGE(cur ^ 1, (t + 1) * 32);

        const f16* sb = &smem[cur][0];
        f16x8 fbh[4], fbl[4];
#pragma unroll
        for (int ni2 = 0; ni2 < 4; ++ni2) {
            int offb = 8192 + (wcg + ni2) * 512 + fro;
            fbh[ni2] = *(const f16x8*)(sb + offb);
            fbl[ni2] = *(const f16x8*)(sb + offb + 4096);
        }
#pragma unroll
        for (int mi2 = 0; mi2 < 4; ++mi2) {
            int offa = (wrg + mi2) * 512 + fro;
            f16x8 fah = *(const f16x8*)(sb + offa);
            f16x8 fal = *(const f16x8*)(sb + offa + 4096);
            __builtin_amdgcn_s_setprio(1);
#pragma unroll
            for (int ni2 = 0; ni2 < 4; ++ni2) {
                accm[mi2][ni2] = MFMA16(fah, fbh[ni2], accm[mi2][ni2]);
                accc[mi2][ni2] = MFMA16(fah, fbl[ni2], accc[mi2][ni2]);
                accc[mi2][ni2] = MFMA16(fal, fbh[ni2], accc[mi2][ni2]);
            }
            __builtin_amdgcn_s_setprio(0);
        }

        __syncthreads();
        cur ^= 1;
    }
#undef STAGE

    const int wr = (w >> 1) * 64;
    const int wc = (w & 1) * 64;
#pragma unroll
    for (int mi2 = 0; mi2 < 4; ++mi2) {
        int row = m0 + wr + mi2 * 16 + lg * 4;
#pragma unroll
        for (int ni2 = 0; ni2 < 4; ++ni2) {
            int col = n0 + wc + ni2 * 16 + l15;
            float bv = bias[col];
#pragma unroll
            for (int j = 0; j < 4; ++j) {
                float val = accm[mi2][ni2][j] + accc[mi2][ni2][j] * INV_LO_SCALE + bv;
                epi_write<EPI>(val, row + j, col, N, C, Oh, Ol, X2h, X2l, X3h, X3l);
            }
        }
    }
}

// ---------------------------------------------------------------------------
// MFMA attention (V arrives [bh][l][d]; transpose during LDS staging).
// ---------------------------------------------------------------------------
__global__ __launch_bounds__(256, 1)
void attn_mfma_kernel(const f16* __restrict__ Qh, const f16* __restrict__ Ql,
                      const f16* __restrict__ Kh, const f16* __restrict__ Kl,
                      const f16* __restrict__ Vh, const f16* __restrict__ Vl,
                      f16* __restrict__ ch, f16* __restrict__ cl)
{
    __shared__ f16 sKh[256 * 72];
    __shared__ f16 sKl[256 * 72];
    __shared__ f16 sVh[64 * 264];
    __shared__ f16 sVl[64 * 264];
    __shared__ f16 sPh[4][1280];
    __shared__ f16 sPl[4][1280];

    const int bh = blockIdx.x >> 1;
    const int qbase = (blockIdx.x & 1) * 128;
    const int b = bh / 12;
    const int h = bh % 12;
    const int tid = threadIdx.x;
    const int w = tid >> 6;
    const int l = tid & 63;
    const int l15 = l & 15;
    const int lg = l >> 4;

    {
        const f16* gKh = Kh + (size_t)bh * 16384;
        const f16* gKl = Kl + (size_t)bh * 16384;
#pragma unroll
        for (int i = 0; i < 8; ++i) {
            int c = tid + i * 256;
            int off = (c >> 3) * 72 + (c & 7) * 8;
            *(f16x8*)(sKh + off) = *(const f16x8*)(gKh + c * 8);
            *(f16x8*)(sKl + off) = *(const f16x8*)(gKl + c * 8);
        }
        const f16* gVh = Vh + (size_t)bh * 16384;
        const f16* gVl = Vl + (size_t)bh * 16384;
#pragma unroll
        for (int i = 0; i < 8; ++i) {
            int c = tid + i * 256;
            int l2 = c >> 3;
            int d0 = (c & 7) * 8;
            f16x8 vh = *(const f16x8*)(gVh + l2 * 64 + d0);
            f16x8 vl = *(const f16x8*)(gVl + l2 * 64 + d0);
#pragma unroll
            for (int j = 0; j < 8; ++j) {
                sVh[(d0 + j) * 264 + l2] = vh[j];
                sVl[(d0 + j) * 264 + l2] = vl[j];
            }
        }
    }
    __syncthreads();

    f16x8 qfh[2][2], qfl[2][2];
#pragma unroll
    for (int mt = 0; mt < 2; ++mt) {
        int qr = qbase + w * 32 + mt * 16 + l15;
        size_t qo = ((size_t)bh * 256 + qr) * 64 + lg * 8;
        qfh[mt][0] = *(const f16x8*)(Qh + qo);
        qfh[mt][1] = *(const f16x8*)(Qh + qo + 32);
        qfl[mt][0] = *(const f16x8*)(Ql + qo);
        qfl[mt][1] = *(const f16x8*)(Ql + qo + 32);
    }

    f32x4 S[2][16];
#pragma unroll
    for (int nt = 0; nt < 16; ++nt) {
        int kr = nt * 16 + l15;
        int kaddr = kr * 72 + lg * 8;
        f16x8 kh0 = *(const f16x8*)(sKh + kaddr);
        f16x8 kh1 = *(const f16x8*)(sKh + kaddr + 32);
        f16x8 kl0 = *(const f16x8*)(sKl + kaddr);
        f16x8 kl1 = *(const f16x8*)(sKl + kaddr + 32);
#pragma unroll
        for (int mt = 0; mt < 2; ++mt) {
            f32x4 am = (f32x4){0.f, 0.f, 0.f, 0.f};
            f32x4 ac = (f32x4){0.f, 0.f, 0.f, 0.f};
            am = MFMA16(qfh[mt][0], kh0, am);
            am = MFMA16(qfh[mt][1], kh1, am);
            ac = MFMA16(qfh[mt][0], kl0, ac);
            ac = MFMA16(qfh[mt][1], kl1, ac);
            ac = MFMA16(qfl[mt][0], kh0, ac);
            ac = MFMA16(qfl[mt][1], kh1, ac);
            S[mt][nt] = (am + ac * INV_LO_SCALE) * 0.125f;
        }
    }

#pragma unroll
    for (int mt = 0; mt < 2; ++mt)
#pragma unroll
        for (int j = 0; j < 4; ++j) {
            float m = S[mt][0][j];
#pragma unroll
            for (int nt = 1; nt < 16; ++nt) m = fmaxf(m, S[mt][nt][j]);
            m = fmaxf(m, __shfl_xor(m, 1));
            m = fmaxf(m, __shfl_xor(m, 2));
            m = fmaxf(m, __shfl_xor(m, 4));
            m = fmaxf(m, __shfl_xor(m, 8));
            float s = 0.f;
#pragma unroll
            for (int nt = 0; nt < 16; ++nt) {
                float e = fexp2((S[mt][nt][j] - m) * LOG2E);
                S[mt][nt][j] = e;
                s += e;
            }
            s += __shfl_xor(s, 1);
            s += __shfl_xor(s, 2);
            s += __shfl_xor(s, 4);
            s += __shfl_xor(s, 8);
            float inv = 1.0f / s;
#pragma unroll
            for (int nt = 0; nt < 16; ++nt) S[mt][nt][j] *= inv;
        }

    f32x4 Ohh[2][4], Occ[2][4];
#pragma unroll
    for (int mt = 0; mt < 2; ++mt)
#pragma unroll
        for (int dt = 0; dt < 4; ++dt) {
            Ohh[mt][dt] = (f32x4){0.f, 0.f, 0.f, 0.f};
            Occ[mt][dt] = (f32x4){0.f, 0.f, 0.f, 0.f};
        }

    f16* pbh = &sPh[w][0];
    f16* pbl = &sPl[w][0];
#pragma unroll
    for (int kp = 0; kp < 8; ++kp) {
#pragma unroll
        for (int mt = 0; mt < 2; ++mt)
#pragma unroll
            for (int n2 = 0; n2 < 2; ++n2) {
                int nt = kp * 2 + n2;
#pragma unroll
                for (int j = 0; j < 4; ++j) {
                    int prow = mt * 16 + lg * 4 + j;
                    int pcol = n2 * 16 + l15;
                    f16 hi, lo;
                    split1(S[mt][nt][j], hi, lo);
                    pbh[prow * 40 + pcol] = hi;
                    pbl[prow * 40 + pcol] = lo;
                }
            }
        __builtin_amdgcn_wave_barrier();
#pragma unroll
        for (int mt = 0; mt < 2; ++mt) {
            int paddr = (mt * 16 + l15) * 40 + lg * 8;
            f16x8 ph = *(const f16x8*)(pbh + paddr);
            f16x8 pl = *(const f16x8*)(pbl + paddr);
#pragma unroll
            for (int dt = 0; dt < 4; ++dt) {
                int vaddr = (dt * 16 + l15) * 264 + kp * 32 + lg * 8;
                f16x8 vh = *(const f16x8*)(sVh + vaddr);
                f16x8 vl = *(const f16x8*)(sVl + vaddr);
                Ohh[mt][dt] = MFMA16(ph, vh, Ohh[mt][dt]);
                Occ[mt][dt] = MFMA16(ph, vl, Occ[mt][dt]);
                Occ[mt][dt] = MFMA16(pl, vh, Occ[mt][dt]);
            }
        }
        __builtin_amdgcn_wave_barrier();
    }

#pragma unroll
    for (int mt = 0; mt < 2; ++mt)
#pragma unroll
        for (int dt = 0; dt < 4; ++dt) {
            f32x4 o = Ohh[mt][dt] + Occ[mt][dt] * INV_LO_SCALE;
#pragma unroll
            for (int j = 0; j < 4; ++j) {
                int q = qbase + w * 32 + mt * 16 + lg * 4 + j;
                int d = dt * 16 + l15;
                size_t off = ((size_t)(b * 256 + q)) * 768 + h * 64 + d;
                f16 hi, lo;
                split1(o[j], hi, lo);
                ch[off] = hi;
                cl[off] = lo;
            }
        }
}

// ---------------------------------------------------------------------------
// Transpose+split, 64x64 tiles, 16 outputs/thread, f16x8 (16B) stores.
// ---------------------------------------------------------------------------
__device__ __forceinline__ void tsplit64_tile(const float* __restrict__ W,
                                              f16* __restrict__ Th, f16* __restrict__ Tl,
                                              int K, int N, int kb, int nb, int tid,
                                              float (*tile)[65])
{
    const int k0 = kb * 64;
    const int n0 = nb * 64;
    const int r = tid >> 2;
    const int c16 = (tid & 3) * 16;
#pragma unroll
    for (int j = 0; j < 16; j += 4) {
        float4 v = *(const float4*)&W[(size_t)(k0 + r) * N + n0 + c16 + j];
        tile[r][c16 + j + 0] = v.x;
        tile[r][c16 + j + 1] = v.y;
        tile[r][c16 + j + 2] = v.z;
        tile[r][c16 + j + 3] = v.w;
    }
    __syncthreads();
    const int n = tid >> 2;
    const int k16 = (tid & 3) * 16;
    f16 hs[16], ls[16];
#pragma unroll
    for (int j = 0; j < 16; ++j) split1(tile[k16 + j][n], hs[j], ls[j]);
    size_t o = (size_t)(n0 + n) * K + k0 + k16;
    *(f16x8*)(Th + o)     = (f16x8){hs[0], hs[1], hs[2], hs[3], hs[4], hs[5], hs[6], hs[7]};
    *(f16x8*)(Th + o + 8) = (f16x8){hs[8], hs[9], hs[10], hs[11], hs[12], hs[13], hs[14], hs[15]};
    *(f16x8*)(Tl + o)     = (f16x8){ls[0], ls[1], ls[2], ls[3], ls[4], ls[5], ls[6], ls[7]};
    *(f16x8*)(Tl + o + 8) = (f16x8){ls[8], ls[9], ls[10], ls[11], ls[12], ls[13], ls[14], ls[15]};
}

// per-layer split-weight element offsets (f16 units)
#define OFF_QKV_H 0
#define OFF_QKV_L 1769472
#define OFF_WO_H  3538944
#define OFF_WO_L  4128768
#define OFF_W1_H  4718592
#define OFF_W1_L  7077888
#define OFF_W2_H  9437184
#define OFF_W2_L  11796480
#define WL_STRIDE 14155776   // f16 elems per layer (28.3 MB)

__global__ void tsplit_all_kernel(const float* __restrict__ Wq, const float* __restrict__ Wk,
                                  const float* __restrict__ Wv, const float* __restrict__ Wo,
                                  const float* __restrict__ W1, const float* __restrict__ W2,
                                  f16* __restrict__ wout, size_t outStride)
{
    __shared__ float tile[64][65];
    const int tid = threadIdx.x;
    const int layer = blockIdx.y;
    const size_t o768 = (size_t)layer * 589824;
    const size_t o3072 = (size_t)layer * 2359296;
    f16* base = wout + (size_t)layer * outStride;
    int bid = blockIdx.x;
    if (bid < 144) {
        tsplit64_tile(Wq + o768, base + OFF_QKV_H, base + OFF_QKV_L,
                      768, 768, bid % 12, bid / 12, tid, tile);
    } else if (bid < 288) {
        bid -= 144;
        tsplit64_tile(Wk + o768, base + OFF_QKV_H + 768 * 768, base + OFF_QKV_L + 768 * 768,
                      768, 768, bid % 12, bid / 12, tid, tile);
    } else if (bid < 432) {
        bid -= 288;
        tsplit64_tile(Wv + o768, base + OFF_QKV_H + 2 * 768 * 768, base + OFF_QKV_L + 2 * 768 * 768,
                      768, 768, bid % 12, bid / 12, tid, tile);
    } else if (bid < 576) {
        bid -= 432;
        tsplit64_tile(Wo + o768, base + OFF_WO_H, base + OFF_WO_L,
                      768, 768, bid % 12, bid / 12, tid, tile);
    } else if (bid < 1152) {
        bid -= 576;
        tsplit64_tile(W1 + o3072, base + OFF_W1_H, base + OFF_W1_L,
                      768, 3072, bid % 12, bid / 12, tid, tile);
    } else {
        bid -= 1152;
        tsplit64_tile(W2 + o3072, base + OFF_W2_H, base + OFF_W2_L,
                      3072, 768, bid % 48, bid / 48, tid, tile);
    }
}

__global__ void pack_qkv_bias_kernel(const float* __restrict__ bq, const float* __restrict__ bk,
                                     const float* __restrict__ bv, float* __restrict__ qkvb)
{
    const int i = blockIdx.x;
    const int tid = threadIdx.x;
    for (int c = tid; c < 768; c += 256) {
        qkvb[i * 2304 + c]        = bq[i * 768 + c];
        qkvb[i * 2304 + 768 + c]  = bk[i * 768 + c];
        qkvb[i * 2304 + 1536 + c] = bv[i * 768 + c];
    }
}

// ---------------------------------------------------------------------------
// Wave-per-token LayerNorm: zero barriers, vector IO.
// ---------------------------------------------------------------------------
__device__ __forceinline__ void ln_wave_core(float v[12], const float* __restrict__ g,
                                             const float* __restrict__ be,
                                             float* __restrict__ x,
                                             f16* __restrict__ xh, f16* __restrict__ xl,
                                             size_t base, int cb)
{
    float s = 0.f;
#pragma unroll
    for (int j = 0; j < 12; ++j) s += v[j];
#pragma unroll
    for (int off = 32; off > 0; off >>= 1) s += __shfl_xor(s, off);
    const float mu = s * (1.0f / 768.0f);
    float d2 = 0.f;
#pragma unroll
    for (int j = 0; j < 12; ++j) { float d = v[j] - mu; d2 += d * d; }
#pragma unroll
    for (int off = 32; off > 0; off >>= 1) d2 += __shfl_xor(d2, off);
    const float rstd = 1.0f / sqrtf(d2 * (1.0f / 768.0f) + 1e-12f);

    const float4* ga = (const float4*)(g + cb);
    const float4* ba = (const float4*)(be + cb);
    float o[12];
#pragma unroll
    for (int j = 0; j < 3; ++j) {
        float4 gg = ga[j];
        float4 bb = ba[j];
        o[j * 4 + 0] = (v[j * 4 + 0] - mu) * rstd * gg.x + bb.x;
        o[j * 4 + 1] = (v[j * 4 + 1] - mu) * rstd * gg.y + bb.y;
        o[j * 4 + 2] = (v[j * 4 + 2] - mu) * rstd * gg.z + bb.z;
        o[j * 4 + 3] = (v[j * 4 + 3] - mu) * rstd * gg.w + bb.w;
    }
    float4* xo = (float4*)(x + base);
#pragma unroll
    for (int j = 0; j < 3; ++j)
        xo[j] = (float4){o[j * 4 + 0], o[j * 4 + 1], o[j * 4 + 2], o[j * 4 + 3]};

    f16 ho[12], lo[12];
#pragma unroll
    for (int j = 0; j < 12; ++j) split1(o[j], ho[j], lo[j]);
#pragma unroll
    for (int j = 0; j < 3; ++j) {
        *(f16x4*)(xh + base + j * 4) = (f16x4){ho[j * 4], ho[j * 4 + 1], ho[j * 4 + 2], ho[j * 4 + 3]};
        *(f16x4*)(xl + base + j * 4) = (f16x4){lo[j * 4], lo[j * 4 + 1], lo[j * 4 + 2], lo[j * 4 + 3]};
    }
}

__global__ __launch_bounds__(256)
void res_ln_w(float* __restrict__ x, const float* __restrict__ y,
              const float* __restrict__ g, const float* __restrict__ be,
              f16* __restrict__ xh, f16* __restrict__ xl)
{
    const int tok = blockIdx.x * 4 + (threadIdx.x >> 6);
    const int cb = (threadIdx.x & 63) * 12;
    const size_t base = (size_t)tok * 768 + cb;
    const float4* xa = (const float4*)(x + base);
    const float4* ya = (const float4*)(y + base);
    float v[12];
#pragma unroll
    for (int j = 0; j < 3; ++j) {
        float4 a = xa[j];
        float4 b2 = ya[j];
        v[j * 4 + 0] = a.x + b2.x;
        v[j * 4 + 1] = a.y + b2.y;
        v[j * 4 + 2] = a.z + b2.z;
        v[j * 4 + 3] = a.w + b2.w;
    }
    ln_wave_core(v, g, be, x, xh, xl, base, cb);
}

__global__ __launch_bounds__(256)
void embed_ln_w(const int* __restrict__ datas, const float* __restrict__ wemb,
                const float* __restrict__ pemb, const float* __restrict__ temb,
                const float* __restrict__ g, const float* __restrict__ be,
                float* __restrict__ x, f16* __restrict__ xh, f16* __restrict__ xl)
{
    const int tok = blockIdx.x * 4 + (threadIdx.x >> 6);
    const int cb = (threadIdx.x & 63) * 12;
    const size_t base = (size_t)tok * 768 + cb;
    const int widx = datas[tok];
    const int l = tok & 255;
    const float4* wa = (const float4*)(wemb + (size_t)widx * 768 + cb);
    const float4* pa = (const float4*)(pemb + (size_t)l * 768 + cb);
    const float4* ta = (const float4*)(temb + cb);
    float v[12];
#pragma unroll
    for (int j = 0; j < 3; ++j) {
        float4 a = wa[j];
        float4 b2 = pa[j];
        float4 c2 = ta[j];
        v[j * 4 + 0] = a.x + b2.x + c2.x;
        v[j * 4 + 1] = a.y + b2.y + c2.y;
        v[j * 4 + 2] = a.z + b2.z + c2.z;
        v[j * 4 + 3] = a.w + b2.w + c2.w;
    }
    ln_wave_core(v, g, be, x, xh, xl, base, cb);
}

// ---------------------------------------------------------------------------
// CRF heads + scans + loss (unchanged)
// ---------------------------------------------------------------------------
__global__ void head_kernel(const float* __restrict__ X, const float* __restrict__ Wh,
                            const float* __restrict__ bh, float* __restrict__ out, int T)
{
    __shared__ float xs[768];
    __shared__ double part[8][32];
    const int i = blockIdx.x;
    const int tid = threadIdx.x;
    for (int c = tid; c < 768; c += 256) xs[c] = X[(size_t)i * 768 + c];
    __syncthreads();
    const int p = tid >> 5;
    const int tg = tid & 31;
    if (tg < T) {
        double a = 0;
        for (int d = p * 96; d < p * 96 + 96; ++d)
            a += (double)xs[d] * (double)Wh[d * T + tg];
        part[p][tg] = a;
    }
    __syncthreads();
    if (tid < T) {
        double s = 0;
        for (int pp = 0; pp < 8; ++pp) s += part[pp][tid];
        out[(size_t)i * T + tid] = (float)(s + (double)bh[tid]);
    }
}

__global__ void crf_num_kernel(const float* __restrict__ em, const int* __restrict__ labels,
                               const float* __restrict__ start, const float* __restrict__ endv,
                               const float* __restrict__ trans, float* __restrict__ num, int T)
{
    __shared__ double red[256];
    const int b = blockIdx.x;
    const int tid = threadIdx.x;
    const int tag = labels[b * 256 + tid];
    float v;
    if (tid == 0) {
        v = start[tag] + em[(size_t)(b * 256) * T + tag];
    } else {
        int pt = labels[b * 256 + tid - 1];
        v = trans[pt * T + tag] + em[(size_t)(b * 256 + tid) * T + tag];
    }
    red[tid] = (double)v;
    __syncthreads();
    for (int st = 128; st > 0; st >>= 1) { if (tid < st) red[tid] += red[tid + st]; __syncthreads(); }
    if (tid == 0) num[b] = (float)(red[0] + (double)endv[labels[b * 256 + 255]]);
}

template<int T>
__global__ void crf_scan_kernel(const float* __restrict__ emG, const float* __restrict__ start,
                                const float* __restrict__ endv, const float* __restrict__ trans,
                                float* __restrict__ den, float* __restrict__ tagOut)
{
    __shared__ float ems[256 * T];
    __shared__ float albuf[32];
    __shared__ unsigned char hist[255 * T + 1];
    const int b = blockIdx.x;
    const bool vit = (blockIdx.y == 1);
    const int c = threadIdx.x;

    for (int idx = c; idx < 256 * T; idx += 64)
        ems[idx] = emG[(size_t)b * 256 * T + idx];
    float trc[T];
#pragma unroll
    for (int p = 0; p < T; ++p) trc[p] = (c < T) ? trans[p * T + c] : 0.f;
    const float ec = (c < T) ? endv[c] : -1e30f;
    __syncthreads();

    float alpha = (c < T) ? (start[c] + ems[c]) : -1e30f;

    if (!vit) {
        for (int t = 1; t < 256; ++t) {
            if (c < T) albuf[c] = alpha;
            __builtin_amdgcn_wave_barrier();
            float a[T];
            float m = -1e30f;
#pragma unroll
            for (int p = 0; p < T; ++p) { a[p] = albuf[p] + trc[p]; m = fmaxf(m, a[p]); }
            float s = 0.f;
#pragma unroll
            for (int p = 0; p < T; ++p) s += fexp2((a[p] - m) * LOG2E);
            float na = m + flog2(s) * 0.6931471805599453f + ems[t * T + c];
            __builtin_amdgcn_wave_barrier();
            if (c < T) alpha = na;
        }
        if (c < T) albuf[c] = alpha + ec;
        __builtin_amdgcn_wave_barrier();
        if (c == 0) {
            float m = -1e30f;
            for (int p = 0; p < T; ++p) m = fmaxf(m, albuf[p]);
            float s = 0.f;
            for (int p = 0; p < T; ++p) s += fexp2((albuf[p] - m) * LOG2E);
            den[b] = m + flog2(s) * 0.6931471805599453f;
        }
    } else {
        for (int t = 1; t < 256; ++t) {
            if (c < T) albuf[c] = alpha;
            __builtin_amdgcn_wave_barrier();
            float best = albuf[0] + trc[0];
            int arg = 0;
#pragma unroll
            for (int p = 1; p < T; ++p) {
                float v2 = albuf[p] + trc[p];
                if (v2 > best) { best = v2; arg = p; }
            }
            __builtin_amdgcn_wave_barrier();
            if (c < T) {
                alpha = best + ems[t * T + c];
                hist[(t - 1) * T + c] = (unsigned char)arg;
            }
        }
        if (c < T) albuf[c] = alpha + ec;
        __builtin_amdgcn_wave_barrier();
        if (c == 0) {
            float bv = albuf[0];
            int cur = 0;
            for (int p = 1; p < T; ++p) {
                if (albuf[p] > bv) { bv = albuf[p]; cur = p; }
            }
            tagOut[b * 256 + 255] = (float)cur;
            for (int t = 254; t >= 0; --t) {
                cur = hist[t * T + cur];
                tagOut[b * 256 + t] = (float)cur;
            }
        }
    }
}

__global__ void loss_kernel(const float* __restrict__ num, const float* __restrict__ den,
                            float* __restrict__ out)
{
    __shared__ double red[32];
    const int tid = threadIdx.x;
    red[tid] = (double)num[tid] - (double)den[tid];
    __syncthreads();
    for (int st = 16; st > 0; st >>= 1) { if (tid < st) red[tid] += red[tid + st]; __syncthreads(); }
    if (tid == 0) out[0] = (float)(-red[0]);
}

// ---------------------------------------------------------------------------
extern "C" void kernel_launch(void* const* d_in, const int* in_sizes, int n_in,
                              void* d_out, int out_size, void* d_ws, size_t ws_size,
                              hipStream_t stream)
{
    (void)in_sizes; (void)n_in; (void)out_size;
    const int* datas       = (const int*)d_in[0];
    const int* ele_labels  = (const int*)d_in[1];
    const int* role_labels = (const int*)d_in[2];
    // d_in[3] seq_mask: all ones
    const float* word_emb = (const float*)d_in[4];
    const float* pos_emb  = (const float*)d_in[5];
    const float* type_emb = (const float*)d_in[6];
    const float* emb_g = (const float*)d_in[7];
    const float* emb_b = (const float*)d_in[8];
    const float* Wq = (const float*)d_in[9];  const float* bq = (const float*)d_in[10];
    const float* Wk = (const float*)d_in[11]; const float* bk = (const float*)d_in[12];
    const float* Wv = (const float*)d_in[13]; const float* bv = (const float*)d_in[14];
    const float* Wo = (const float*)d_in[15]; const float* bo = (const float*)d_in[16];
    const float* ln1g = (const float*)d_in[17]; const float* ln1b = (const float*)d_in[18];
    const float* W1 = (const float*)d_in[19]; const float* b1 = (const float*)d_in[20];
    const float* W2 = (const float*)d_in[21]; const float* b2 = (const float*)d_in[22];
    const float* ln2g = (const float*)d_in[23]; const float* ln2b = (const float*)d_in[24];
    const float* W_ele = (const float*)d_in[25]; const float* b_ele = (const float*)d_in[26];
    const float* W_role = (const float*)d_in[27]; const float* b_role = (const float*)d_in[28];
    const float* ele_start = (const float*)d_in[29];
    const float* ele_end   = (const float*)d_in[30];
    const float* ele_trans = (const float*)d_in[31];
    const float* role_start = (const float*)d_in[32];
    const float* role_end   = (const float*)d_in[33];
    const float* role_trans = (const float*)d_in[34];
    float* out = (float*)d_out;

    uint8_t* ws = (uint8_t*)d_ws;
    float* x      = (float*)(ws + 0x0000000);   // 4096x768 f32
    f16* xh       = (f16*)  (ws + 0x0C00000);
    f16* xl       = (f16*)  (ws + 0x1200000);
    f16* Qh       = (f16*)  (ws + 0x1800000);   // [b,h,l,d] f16
    f16* Ql       = (f16*)  (ws + 0x1E00000);
    f16* Kh       = (f16*)  (ws + 0x2400000);
    f16* Kl       = (f16*)  (ws + 0x2A00000);
    f16* Vh       = (f16*)  (ws + 0x3000000);   // [b,h,l,d] f16 (attn transposes)
    f16* Vl       = (f16*)  (ws + 0x3600000);
    f16* ctxh     = (f16*)  (ws + 0x3C00000);   // [token][768]
    f16* ctxl     = (f16*)  (ws + 0x4200000);
    float* rbuf   = (float*)(ws + 0x4800000);   // 4096x768 f32 (ends 0x5400000)
    f16* hh       = (f16*)  (ws + 0x1800000);   // 4096x3072 (over Qh..Kl)
    f16* hl       = (f16*)  (ws + 0x3000000);   // (over Vh..ctxl)
    float* qkvb   = (float*)(ws + 0x5400000);   // 12x2304
    float* ele_em = (float*)(ws + 0x5420000);   // 4096x17
    float* role_em= (float*)(ws + 0x5468000);   // 4096x7
    float* numb   = (float*)(ws + 0x5484000);   // [32]
    float* denb   = (float*)(ws + 0x5484100);   // [32]
    f16* wsplit   = (f16*)  (ws + 0x5490000);   // split weights: 1 or 12 layers

    const bool hoist = ws_size >= (0x5490000ull + 12ull * WL_STRIDE * 2ull + 0x10000ull);

    pack_qkv_bias_kernel<<<12, 256, 0, stream>>>(bq, bk, bv, qkvb);
    embed_ln_w<<<1024, 256, 0, stream>>>(datas, word_emb, pos_emb, type_emb,
                                         emb_g, emb_b, x, xh, xl);
    if (hoist)
        tsplit_all_kernel<<<dim3(1728, 12), 256, 0, stream>>>(Wq, Wk, Wv, Wo, W1, W2,
                                                              wsplit, WL_STRIDE);

    for (int i = 0; i < 12; ++i) {
        if (!hoist)
            tsplit_all_kernel<<<dim3(1728, 1), 256, 0, stream>>>(
                Wq + (size_t)i * 589824, Wk + (size_t)i * 589824,
                Wv + (size_t)i * 589824, Wo + (size_t)i * 589824,
                W1 + (size_t)i * 2359296, W2 + (size_t)i * 2359296,
                wsplit, 0);
        f16* wl = wsplit + (hoist ? (size_t)i * WL_STRIDE : 0);

        // QKV fused: [4096x768] @ [768x2304] -> split f16 Q/K/V head-major
        gemm128<2><<<dim3(32, 18), 256, 0, stream>>>(xh, xl, wl + OFF_QKV_H, wl + OFF_QKV_L,
                                                     qkvb + i * 2304, nullptr,
                                                     Qh, Ql, Kh, Kl, Vh, Vl, 768, 2304);
        attn_mfma_kernel<<<384, 256, 0, stream>>>(Qh, Ql, Kh, Kl, Vh, Vl, ctxh, ctxl);
        gemm128<0><<<dim3(32, 6), 256, 0, stream>>>(ctxh, ctxl, wl + OFF_WO_H, wl + OFF_WO_L,
                                                    bo + i * 768, rbuf, nullptr, nullptr,
                                                    nullptr, nullptr, nullptr, nullptr, 768, 768);
        res_ln_w<<<1024, 256, 0, stream>>>(x, rbuf, ln1g + i * 768, ln1b + i * 768, xh, xl);
        // FF1 with fused GELU+split epilogue
        gemm128<1><<<dim3(32, 24), 256, 0, stream>>>(xh, xl, wl + OFF_W1_H, wl + OFF_W1_L,
                                                     b1 + i * 3072, nullptr, hh, hl,
                                                     nullptr, nullptr, nullptr, nullptr, 768, 3072);
        gemm128<0><<<dim3(32, 6), 256, 0, stream>>>(hh, hl, wl + OFF_W2_H, wl + OFF_W2_L,
                                                    b2 + i * 768, rbuf, nullptr, nullptr,
                                                    nullptr, nullptr, nullptr, nullptr, 3072, 768);
        res_ln_w<<<1024, 256, 0, stream>>>(x, rbuf, ln2g + i * 768, ln2b + i * 768, xh, xl);
    }

    head_kernel<<<4096, 256, 0, stream>>>(x, W_ele, b_ele, ele_em, 17);
    head_kernel<<<4096, 256, 0, stream>>>(x, W_role, b_role, role_em, 7);

    crf_num_kernel<<<16, 256, 0, stream>>>(ele_em, ele_labels, ele_start, ele_end, ele_trans, numb, 17);
    crf_num_kernel<<<16, 256, 0, stream>>>(role_em, role_labels, role_start, role_end, role_trans, numb + 16, 7);
    crf_scan_kernel<17><<<dim3(16, 2), 64, 0, stream>>>(ele_em, ele_start, ele_end, ele_trans, denb, out + 1);
    crf_scan_kernel<7><<<dim3(16, 2), 64, 0, stream>>>(role_em, role_start, role_end, role_trans, denb + 16, out + 1 + 4096);
    loss_kernel<<<1, 32, 0, stream>>>(numb, denb, out);
}